// Round 2
// baseline (411.723 us; speedup 1.0000x reference)
//
#include <hip/hip_runtime.h>

typedef unsigned int u32;

#define BB   2
#define NN   50000
#define EE   800000
#define INCH 64
#define C1   16
#define C2   32
#define NB   (BB*NN)

// workspace layout (float offsets)
#define OFF_XS1   0
#define OFF_AGGR1 (OFF_XS1   + NB*C1)
#define OFF_DOTK1 (OFF_AGGR1 + NB*C1)
#define OFF_DOTQ1 (OFF_DOTK1 + NB)
#define OFF_XS2   (OFF_DOTQ1 + NB)
#define OFF_AGGR2 (OFF_XS2   + NB*C2)
#define OFF_DOTK2 (OFF_AGGR2 + NB*C2)
#define OFF_DOTQ2 (OFF_DOTK2 + NB)
#define OFF_COMBO (OFF_DOTQ2 + NB)
// combo: [0:16] kv1, [16:32] qv1, [32:64] kv2, [64:96] qv2, [96] ec1, [97] ec2

__device__ __forceinline__ float sigmoidf(float x) {
    return 1.0f / (1.0f + __expf(-x));
}

// ---------------- tiny combo precompute --------------------------------------
__global__ void k_combos(const float* __restrict__ key1, const float* __restrict__ query1,
                         const float* __restrict__ we1,  const float* __restrict__ aw1,
                         const float* __restrict__ key2, const float* __restrict__ query2,
                         const float* __restrict__ we2,  const float* __restrict__ aw2,
                         float* __restrict__ combo) {
    int c = threadIdx.x;
    if (c < C1) {
        float kv = 0.f, qv = 0.f;
        for (int j = 0; j < C1; ++j) {
            kv += key1[c*C1+j]   * aw1[j];
            qv += query1[c*C1+j] * aw1[C1+j];
        }
        combo[c] = kv; combo[16+c] = qv;
    }
    if (c < C2) {
        float kv = 0.f, qv = 0.f;
        for (int j = 0; j < C2; ++j) {
            kv += key2[c*C2+j]   * aw2[j];
            qv += query2[c*C2+j] * aw2[C2+j];
        }
        combo[32+c] = kv; combo[64+c] = qv;
    }
    if (c == 0) {
        float e1 = 0.f, e2 = 0.f;
        for (int j = 0; j < C1; ++j) e1 += we1[j] * aw1[2*C1+j];
        for (int j = 0; j < C2; ++j) e2 += we2[j] * aw2[2*C2+j];
        combo[96] = e1; combo[97] = e2;
    }
}

// ---------------- layer 1: xs1 = X @ value1, plus per-node att dots ----------
__global__ __launch_bounds__(256) void k_value1(
        const float* __restrict__ X, const float* __restrict__ value1,
        const float* __restrict__ combo,
        float* __restrict__ xs1, float* __restrict__ dotk1, float* __restrict__ dotq1) {
    __shared__ float W[INCH*C1];
    __shared__ float KV[C1], QV[C1];
    int tid = threadIdx.x;
    for (int i = tid; i < INCH*C1; i += 256) W[i] = value1[i];
    if (tid < C1) { KV[tid] = combo[tid]; QV[tid] = combo[16+tid]; }
    __syncthreads();
    int bn = blockIdx.x * 256 + tid;
    if (bn >= NB) return;
    const float4* Xr = (const float4*)(X + (size_t)bn * INCH);
    float acc[C1];
#pragma unroll
    for (int j = 0; j < C1; ++j) acc[j] = 0.f;
#pragma unroll
    for (int v = 0; v < 16; ++v) {          // 16 × float4 = 64 floats
        float4 p = Xr[v];
        float x4[4] = {p.x, p.y, p.z, p.w};
#pragma unroll
        for (int h = 0; h < 4; ++h) {
            int i = v*4 + h;
            float xv = x4[h];
#pragma unroll
            for (int j = 0; j < C1; ++j) acc[j] += xv * W[i*C1+j];
        }
    }
    float dk = 0.f, dq = 0.f;
#pragma unroll
    for (int j = 0; j < C1; ++j) { dk += acc[j]*KV[j]; dq += acc[j]*QV[j]; }
    float4* o = (float4*)(xs1 + (size_t)bn * C1);
#pragma unroll
    for (int v = 0; v < 4; ++v)
        o[v] = make_float4(acc[4*v], acc[4*v+1], acc[4*v+2], acc[4*v+3]);
    dotk1[bn] = dk; dotq1[bn] = dq;
}

// ---------------- edge scatter, layer 1 (16 lanes per edge) ------------------
__global__ __launch_bounds__(256) void k_edge1(
        const int* __restrict__ ei, const float* __restrict__ ew,
        const float* __restrict__ we, const float* __restrict__ ab,
        const float* __restrict__ combo,
        const float* __restrict__ xs, const float* __restrict__ dotk,
        const float* __restrict__ dotq, float* __restrict__ aggr) {
    int t = blockIdx.x * 256 + threadIdx.x;
    int e = t >> 4;
    int c = t & 15;
    if (e >= EE) return;
    int src = ei[e];
    int dst = ei[EE + e];
    float ef    = ew[e];
    float sig_e = sigmoidf(ef * we[c]);
    float ebias = ef * combo[96] + ab[0];
#pragma unroll
    for (int b = 0; b < BB; ++b) {
        float xj    = xs[(size_t)(b*NN + src)*C1 + c];
        float logit = dotk[b*NN + dst] + dotq[b*NN + src] + ebias;
        float att   = sigmoidf(logit);
        atomicAdd(&aggr[(size_t)(b*NN + dst)*C1 + c], att * xj * sig_e);
    }
}

// ---------------- fused: update1 + leaky_relu + xs2 = X1 @ value2 ------------
__global__ __launch_bounds__(256) void k_update1(
        const float* __restrict__ cat_w, const float* __restrict__ cat_b,
        const float* __restrict__ value2, const float* __restrict__ combo,
        const float* __restrict__ xs1, const float* __restrict__ aggr1,
        float* __restrict__ xs2, float* __restrict__ dotk2, float* __restrict__ dotq2) {
    __shared__ float CW[2*C1*C1];   // 32x16
    __shared__ float CB[C1];
    __shared__ float V2[C1*C2];     // 16x32
    __shared__ float KV[C2], QV[C2];
    int tid = threadIdx.x;
    for (int i = tid; i < 2*C1*C1; i += 256) CW[i] = cat_w[i];
    for (int i = tid; i < C1*C2;   i += 256) V2[i] = value2[i];
    if (tid < C1) CB[tid] = cat_b[tid];
    if (tid < C2) { KV[tid] = combo[32+tid]; QV[tid] = combo[64+tid]; }
    __syncthreads();
    int bn = blockIdx.x * 256 + tid;
    if (bn >= NB) return;
    const float4* xr = (const float4*)(xs1   + (size_t)bn * C1);
    const float4* ar = (const float4*)(aggr1 + (size_t)bn * C1);
    float xd[C1], ag[C1];
#pragma unroll
    for (int v = 0; v < 4; ++v) {
        float4 a = xr[v], b = ar[v];
        xd[4*v]=a.x; xd[4*v+1]=a.y; xd[4*v+2]=a.z; xd[4*v+3]=a.w;
        ag[4*v]=b.x; ag[4*v+1]=b.y; ag[4*v+2]=b.z; ag[4*v+3]=b.w;
    }
    float x1[C1];
#pragma unroll
    for (int j = 0; j < C1; ++j) {
        float u = CB[j];
#pragma unroll
        for (int i = 0; i < C1; ++i) {
            u += xd[i] * CW[i*C1 + j];
            u += ag[i] * CW[(C1+i)*C1 + j];
        }
        float o = xd[j] + fmaxf(u, 0.f);
        x1[j] = (o > 0.f) ? o : 0.01f * o;       // leaky_relu
    }
    float o2[C2];
#pragma unroll
    for (int k = 0; k < C2; ++k) o2[k] = 0.f;
#pragma unroll
    for (int j = 0; j < C1; ++j) {
        float xv = x1[j];
#pragma unroll
        for (int k = 0; k < C2; ++k) o2[k] += xv * V2[j*C2 + k];
    }
    float dk = 0.f, dq = 0.f;
#pragma unroll
    for (int k = 0; k < C2; ++k) { dk += o2[k]*KV[k]; dq += o2[k]*QV[k]; }
    float4* o = (float4*)(xs2 + (size_t)bn * C2);
#pragma unroll
    for (int v = 0; v < 8; ++v)
        o[v] = make_float4(o2[4*v], o2[4*v+1], o2[4*v+2], o2[4*v+3]);
    dotk2[bn] = dk; dotq2[bn] = dq;
}

// ---------------- edge scatter, layer 2 (32 lanes per edge) ------------------
__global__ __launch_bounds__(256) void k_edge2(
        const int* __restrict__ ei, const float* __restrict__ ew,
        const float* __restrict__ we, const float* __restrict__ ab,
        const float* __restrict__ combo,
        const float* __restrict__ xs, const float* __restrict__ dotk,
        const float* __restrict__ dotq, float* __restrict__ aggr) {
    int t = blockIdx.x * 256 + threadIdx.x;
    int e = t >> 5;
    int c = t & 31;
    if (e >= EE) return;
    int src = ei[e];
    int dst = ei[EE + e];
    float ef    = ew[e];
    float sig_e = sigmoidf(ef * we[c]);
    float ebias = ef * combo[97] + ab[0];
#pragma unroll
    for (int b = 0; b < BB; ++b) {
        float xj    = xs[(size_t)(b*NN + src)*C2 + c];
        float logit = dotk[b*NN + dst] + dotq[b*NN + src] + ebias;
        float att   = sigmoidf(logit);
        atomicAdd(&aggr[(size_t)(b*NN + dst)*C2 + c], att * xj * sig_e);
    }
}

// ---------------- final: update2 -> fp32 out ---------------------------------
__global__ __launch_bounds__(256) void k_update2(
        const float* __restrict__ cat_w, const float* __restrict__ cat_b,
        const float* __restrict__ xs2, const float* __restrict__ aggr2,
        float* __restrict__ out) {
    __shared__ float CW[2*C2*C2];   // 64x32
    __shared__ float CB[C2];
    int tid = threadIdx.x;
    for (int i = tid; i < 2*C2*C2; i += 256) CW[i] = cat_w[i];
    if (tid < C2) CB[tid] = cat_b[tid];
    __syncthreads();
    int bn = blockIdx.x * 256 + tid;
    if (bn >= NB) return;
    const float4* xr = (const float4*)(xs2   + (size_t)bn * C2);
    const float4* ar = (const float4*)(aggr2 + (size_t)bn * C2);
    float xd[C2], ag[C2];
#pragma unroll
    for (int v = 0; v < 8; ++v) {
        float4 a = xr[v], b = ar[v];
        xd[4*v]=a.x; xd[4*v+1]=a.y; xd[4*v+2]=a.z; xd[4*v+3]=a.w;
        ag[4*v]=b.x; ag[4*v+1]=b.y; ag[4*v+2]=b.z; ag[4*v+3]=b.w;
    }
    float o[C2];
#pragma unroll
    for (int k = 0; k < C2; ++k) {
        float u = CB[k];
#pragma unroll
        for (int i = 0; i < C2; ++i) {
            u += xd[i] * CW[i*C2 + k];
            u += ag[i] * CW[(C2+i)*C2 + k];
        }
        o[k] = xd[k] + fmaxf(u, 0.f);
    }
    float4* dst = (float4*)(out + (size_t)bn * C2);
#pragma unroll
    for (int v = 0; v < 8; ++v)
        dst[v] = make_float4(o[4*v], o[4*v+1], o[4*v+2], o[4*v+3]);
}

extern "C" void kernel_launch(void* const* d_in, const int* in_sizes, int n_in,
                              void* d_out, int out_size, void* d_ws, size_t ws_size,
                              hipStream_t stream) {
    const float* X      = (const float*)d_in[0];
    const int*   ei0    = (const int*)d_in[1];
    const int*   ei1    = (const int*)d_in[2];
    const float* ew0    = (const float*)d_in[3];
    const float* ew1    = (const float*)d_in[4];
    // d_in[5], d_in[6]: res_n_id0/1 == arange(N) -> identity gather, unused
    const float* value1 = (const float*)d_in[7];
    const float* key1   = (const float*)d_in[8];
    const float* query1 = (const float*)d_in[9];
    const float* we1    = (const float*)d_in[10];
    const float* aw1    = (const float*)d_in[11];
    const float* ab1    = (const float*)d_in[12];
    const float* cw1    = (const float*)d_in[13];
    const float* cb1    = (const float*)d_in[14];
    const float* value2 = (const float*)d_in[15];
    const float* key2   = (const float*)d_in[16];
    const float* query2 = (const float*)d_in[17];
    const float* we2    = (const float*)d_in[18];
    const float* aw2    = (const float*)d_in[19];
    const float* ab2    = (const float*)d_in[20];
    const float* cw2    = (const float*)d_in[21];
    const float* cb2    = (const float*)d_in[22];
    float* ws  = (float*)d_ws;
    float* out = (float*)d_out;

    hipMemsetAsync(ws + OFF_AGGR1, 0, (size_t)NB*C1*sizeof(float), stream);
    hipMemsetAsync(ws + OFF_AGGR2, 0, (size_t)NB*C2*sizeof(float), stream);

    k_combos<<<1, 64, 0, stream>>>(key1, query1, we1, aw1, key2, query2, we2, aw2,
                                   ws + OFF_COMBO);
    k_value1<<<(NB+255)/256, 256, 0, stream>>>(X, value1, ws + OFF_COMBO,
                                               ws + OFF_XS1, ws + OFF_DOTK1, ws + OFF_DOTQ1);
    k_edge1<<<(EE*16)/256, 256, 0, stream>>>(ei0, ew0, we1, ab1, ws + OFF_COMBO,
                                             ws + OFF_XS1, ws + OFF_DOTK1, ws + OFF_DOTQ1,
                                             ws + OFF_AGGR1);
    k_update1<<<(NB+255)/256, 256, 0, stream>>>(cw1, cb1, value2, ws + OFF_COMBO,
                                                ws + OFF_XS1, ws + OFF_AGGR1,
                                                ws + OFF_XS2, ws + OFF_DOTK2, ws + OFF_DOTQ2);
    k_edge2<<<(EE*32)/256, 256, 0, stream>>>(ei1, ew1, we2, ab2, ws + OFF_COMBO,
                                             ws + OFF_XS2, ws + OFF_DOTK2, ws + OFF_DOTQ2,
                                             ws + OFF_AGGR2);
    k_update2<<<(NB+255)/256, 256, 0, stream>>>(cw2, cb2, ws + OFF_XS2, ws + OFF_AGGR2, out);
}